// Round 8
// baseline (208.003 us; speedup 1.0000x reference)
//
#include <hip/hip_runtime.h>

#define D256 256
#define TOTROWS 65536   // B*A*I = 4*32*512
#define BM 64           // rows per block = 2 x 32-row tiles
#define LDW 268         // 536B row stride: dword-stride 134 % 32 = 6 -> worst 2-way (free)
#define NBLK (TOTROWS / BM)   // 1024
#define NT 512          // 8 waves: wave = (panel-pair wv&3) x (row-tile wv>>2)

typedef unsigned short u16;
typedef unsigned int u32;
typedef __attribute__((ext_vector_type(8))) short bf16x8;
typedef __attribute__((ext_vector_type(16))) float f32x16;

__device__ __forceinline__ float b2f(u16 u) {
  union { u32 i; float f; } v; v.i = ((u32)u) << 16; return v.f;
}
__device__ __forceinline__ u16 f2b(float f) {
  union { float f; u32 i; } v; v.f = f;
  return (u16)((v.i + 0x7fffu + ((v.i >> 16) & 1u)) >> 16);  // RNE
}
// packed RNE f32x2 -> bf16x2 (single VALU instr; bit-identical to f2b)
__device__ __forceinline__ u32 f2b2(float lo, float hi) {
  u32 r;
  asm("v_cvt_pk_bf16_f32 %0, %1, %2" : "=v"(r) : "v"(lo), "v"(hi));
  return r;
}

// Build weight fragments in MFMA fragment lane order, bf16 (verified r0-r7):
//   Wf[m][p][k][ln] (16B chunk) = Brow[m][col = p*32 + (ln&31)][k*16 + (ln>>5)*8 ..+8]
// Brow[0]=attn1, Brow[1]=attn2 (row-major [n][k]); Brow[2][n][j]=W1[j][n]; Brow[3][n][j]=W2[j][n].
// Serves as B-operand (lane&31 = out col) AND as A-operand (lane&31 = out row)
// since A/B fragment layouts are mutually transposed.
__global__ void build_wfrag(const float* __restrict__ a1,
                            const float* __restrict__ a2,
                            const float* __restrict__ W1,
                            const float* __restrict__ W2,
                            u16* __restrict__ Wf) {
  const int m = blockIdx.y;
  const int idx = blockIdx.x * 256 + threadIdx.x;   // 0..8191 per matrix
  int col, c;
  const float* src;
  if (m < 2) { col = idx >> 5; c = idx & 31; src = m ? a2 : a1; }
  else       { col = idx & 255; c = idx >> 8; src = (m == 3) ? W2 : W1; }
  const int kk0 = c * 8;
  const int p = col >> 5, l31 = col & 31, lhh = c & 1, k = c >> 1;
  const int ln = lhh * 32 + l31;
  u16* dst = Wf + m * 65536 + ((p * 16 + k) * 64 + ln) * 8;
  u16 v[8];
  if (m < 2) {
#pragma unroll
    for (int j = 0; j < 8; j++) v[j] = f2b(src[col * 256 + kk0 + j]);
  } else {
#pragma unroll
    for (int j = 0; j < 8; j++) v[j] = f2b(src[(kk0 + j) * 256 + col]);
  }
  ushort4 lo, hi;
  lo.x = v[0]; lo.y = v[1]; lo.z = v[2]; lo.w = v[3];
  hi.x = v[4]; hi.y = v[5]; hi.z = v[6]; hi.w = v[7];
  ((ushort4*)dst)[0] = lo;
  ((ushort4*)dst)[1] = hi;
}

__global__ __launch_bounds__(NT, 4)
void fused(const float* __restrict__ X0g, const float* __restrict__ X1g,
           const u16* __restrict__ Wf, float* __restrict__ outg) {
  __shared__ u16 lX0[BM][LDW];   // 34.3 KB
  __shared__ u16 lX1[BM][LDW];   // 34.3 KB -> 69.6 KB total, 2 blocks/CU
  __shared__ float sp0[BM], sp1[BM], sc0[BM], sc1[BM];

  const int t = threadIdx.x;
  const int row0 = blockIdx.x * BM;

  if (t < BM) { sp0[t] = 0.f; }
  else if (t < 2 * BM) { sp1[t - BM] = 0.f; }

  // ---- stage: fp32 global -> bf16 LDS (4096 float4/tensor, 8 iters; verified) ----
  {
    const float4* g0 = (const float4*)(X0g + (size_t)row0 * D256);
    const float4* g1 = (const float4*)(X1g + (size_t)row0 * D256);
    uint2* s0 = (uint2*)&lX0[0][0];   // row stride = 67 uint2
    uint2* s1 = (uint2*)&lX1[0][0];
#pragma unroll 4
    for (int i = 0; i < 8; i++) {
      const int e = i * NT + t;         // 64 float4 per row
      const int row = e >> 6;
      const int col = e & 63;
      float4 a = g0[e];
      float4 b = g1[e];
      uint2 pa, pb;
      pa.x = f2b2(a.x, a.y); pa.y = f2b2(a.z, a.w);
      pb.x = f2b2(b.x, b.y); pb.y = f2b2(b.z, b.w);
      s0[row * 67 + col] = pa;
      s1[row * 67 + col] = pb;
    }
  }
  __syncthreads();   // LDS tiles + sp zero-init visible

  const int ln  = t & 63;
  const int wv  = t >> 6;
  const int l31 = ln & 31;
  const int lh  = ln >> 5;
  const int rt  = wv >> 2;          // row-tile 0/1
  const int rb  = rt * 32;          // row base within block
  const int pq  = wv & 3;           // panel pair index
  const int cb0 = (2 * pq) * 32;
  const int cb1 = (2 * pq + 1) * 32;

  // fragment-ordered weight streams: 1KB contiguous per (mat, panel, k)
  const u16* w_[4][2];
#pragma unroll
  for (int m = 0; m < 4; m++) {
#pragma unroll
    for (int pp = 0; pp < 2; pp++) {
      w_[m][pp] = Wf + m * 65536 + ((2 * pq + pp) * 16) * 512 + ln * 8;
    }
  }

  // ---- pass 1: gate scores, SWAPPED operands (G = Z^T, data-row = lane&31).
  // Each a-frag ds_read feeds TWO MFMAs (2 panels): reads/MFMA = 0.5.
  {
    f32x16 G00, G01, G10, G11;
#pragma unroll
    for (int i = 0; i < 16; i++) { G00[i] = 0.f; G01[i] = 0.f;
                                   G10[i] = 0.f; G11[i] = 0.f; }

#pragma unroll 2
    for (int k = 0; k < 16; k++) {
      bf16x8 a0 = *(const bf16x8*)(&lX0[rb + l31][k * 16 + lh * 8]);
      bf16x8 a1 = *(const bf16x8*)(&lX1[rb + l31][k * 16 + lh * 8]);
      bf16x8 w10 = *(const bf16x8*)(w_[0][0] + k * 512);
      bf16x8 w11 = *(const bf16x8*)(w_[0][1] + k * 512);
      bf16x8 w20 = *(const bf16x8*)(w_[1][0] + k * 512);
      bf16x8 w21 = *(const bf16x8*)(w_[1][1] + k * 512);
      G00 = __builtin_amdgcn_mfma_f32_32x32x16_bf16(w10, a0, G00, 0, 0, 0);
      G01 = __builtin_amdgcn_mfma_f32_32x32x16_bf16(w11, a0, G01, 0, 0, 0);
      G10 = __builtin_amdgcn_mfma_f32_32x32x16_bf16(w20, a1, G10, 0, 0, 0);
      G11 = __builtin_amdgcn_mfma_f32_32x32x16_bf16(w21, a1, G11, 0, 0, 0);
    }

    // gate finish: reg r holds j = (r&3)+8*(r>>2)+4*lh within the panel, for
    // data row rb+l31. In-lane dot over both panels, one lh-swap, one atomicAdd.
    {
      const u16* xr1a = &lX1[rb + l31][cb0 + 4 * lh];
      const u16* xr1b = &lX1[rb + l31][cb1 + 4 * lh];
      const u16* xr0a = &lX0[rb + l31][cb0 + 4 * lh];
      const u16* xr0b = &lX0[rb + l31][cb1 + 4 * lh];
      float v0 = 0.f, v1 = 0.f;
#pragma unroll
      for (int g = 0; g < 4; g++) {
        ushort4 a = *(const ushort4*)(xr1a + 8 * g);
        ushort4 b = *(const ushort4*)(xr1b + 8 * g);
        ushort4 c = *(const ushort4*)(xr0a + 8 * g);
        ushort4 d = *(const ushort4*)(xr0b + 8 * g);
        v0 += G00[g * 4 + 0] * b2f(a.x) + G00[g * 4 + 1] * b2f(a.y) +
              G00[g * 4 + 2] * b2f(a.z) + G00[g * 4 + 3] * b2f(a.w);
        v0 += G01[g * 4 + 0] * b2f(b.x) + G01[g * 4 + 1] * b2f(b.y) +
              G01[g * 4 + 2] * b2f(b.z) + G01[g * 4 + 3] * b2f(b.w);
        v1 += G10[g * 4 + 0] * b2f(c.x) + G10[g * 4 + 1] * b2f(c.y) +
              G10[g * 4 + 2] * b2f(c.z) + G10[g * 4 + 3] * b2f(c.w);
        v1 += G11[g * 4 + 0] * b2f(d.x) + G11[g * 4 + 1] * b2f(d.y) +
              G11[g * 4 + 2] * b2f(d.z) + G11[g * 4 + 3] * b2f(d.w);
      }
      v0 += __shfl_xor(v0, 32, 64);   // combine lh halves (j-split)
      v1 += __shfl_xor(v1, 32, 64);
      if (lh == 0) {
        atomicAdd(&sp0[rb + l31], v0);   // combine 4 panel-pair waves
        atomicAdd(&sp1[rb + l31], v1);
      }
    }
  }
  __syncthreads();   // sp complete

  // sigmoid by first 128 threads; other waves proceed into pass 2.
  if (t < BM) {
    sc0[t] = 1.f + 1.f / (1.f + __expf(-sp0[t]));
  } else if (t < 2 * BM) {
    sc1[t - BM] = 1.f + 1.f / (1.f + __expf(-sp1[t - BM]));
  }

  // ---- pass 2: projections (unswapped: col = lane for coalesced stores);
  // same 2-panel a-frag reuse.
  {
    f32x16 P00, P01, P10, P11;
#pragma unroll
    for (int i = 0; i < 16; i++) { P00[i] = 0.f; P01[i] = 0.f;
                                   P10[i] = 0.f; P11[i] = 0.f; }

#pragma unroll 2
    for (int k = 0; k < 16; k++) {
      bf16x8 a0 = *(const bf16x8*)(&lX0[rb + l31][k * 16 + lh * 8]);
      bf16x8 a1 = *(const bf16x8*)(&lX1[rb + l31][k * 16 + lh * 8]);
      bf16x8 u10 = *(const bf16x8*)(w_[2][0] + k * 512);
      bf16x8 u11 = *(const bf16x8*)(w_[2][1] + k * 512);
      bf16x8 u20 = *(const bf16x8*)(w_[3][0] + k * 512);
      bf16x8 u21 = *(const bf16x8*)(w_[3][1] + k * 512);
      P00 = __builtin_amdgcn_mfma_f32_32x32x16_bf16(a0, u10, P00, 0, 0, 0);
      P01 = __builtin_amdgcn_mfma_f32_32x32x16_bf16(a0, u11, P01, 0, 0, 0);
      P10 = __builtin_amdgcn_mfma_f32_32x32x16_bf16(a1, u20, P10, 0, 0, 0);
      P11 = __builtin_amdgcn_mfma_f32_32x32x16_bf16(a1, u21, P11, 0, 0, 0);
    }

    __syncthreads();   // sc0/sc1 ready + visible

#pragma unroll
    for (int pp = 0; pp < 2; pp++) {
      float* opb = outg + (size_t)(row0 + rb) * D256 + (pp ? cb1 : cb0);
#pragma unroll
      for (int q = 0; q < 4; q++) {
        float s0a[4], s1a[4];
        *(float4*)s0a = *(const float4*)&sc0[rb + 8 * q + 4 * lh];
        *(float4*)s1a = *(const float4*)&sc1[rb + 8 * q + 4 * lh];
#pragma unroll
        for (int j = 0; j < 4; j++) {
          const int r = q * 4 + j;
          const int row = j + 8 * q + 4 * lh;
          const float p0 = pp ? P01[r] : P00[r];
          const float p1 = pp ? P11[r] : P10[r];
          __builtin_nontemporal_store(s0a[j] * p0 + s1a[j] * p1,
                                      &opb[row * D256 + l31]);
        }
      }
    }
  }
}

extern "C" void kernel_launch(void* const* d_in, const int* in_sizes, int n_in,
                              void* d_out, int out_size, void* d_ws, size_t ws_size,
                              hipStream_t stream) {
  const float* i0 = (const float*)d_in[0];
  const float* i1 = (const float*)d_in[1];
  const float* W1 = (const float*)d_in[2];
  const float* W2 = (const float*)d_in[3];
  const float* a1 = (const float*)d_in[4];
  const float* a2 = (const float*)d_in[5];
  u16* Wf = (u16*)d_ws;   // 4 x 256x256 bf16 = 512 KB, fragment-ordered

  build_wfrag<<<dim3(32, 4), 256, 0, stream>>>(a1, a2, W1, W2, Wf);
  fused<<<NBLK, NT, 0, stream>>>(i0, i1, Wf, (float*)d_out);
}